// Round 1
// baseline (10613.449 us; speedup 1.0000x reference)
//
#include <hip/hip_runtime.h>
#include <hip/hip_bf16.h>
#include <math.h>

// Problem constants (from reference)
#define HID       300
#define HP        320   // padded hidden (multiple of 64); pad cols are exact zeros
#define NH        4
#define E_BONDS   60000
#define NATOMS    30000
#define KNB       6
#define NMOLS     600
#define APM       50
#define AFD       144
#define BONDIN    158
#define TB        16    // bonds per block in fused MP kernel

// ---------------------------------------------------------------------------
// Weight prep: pad W_ma -> [NH][HP][HP], transpose+pad W_h -> [NH*HP][HP]
// ---------------------------------------------------------------------------
__global__ void prep_wma_k(const float* __restrict__ Wma, float* __restrict__ o) {
    int idx = blockIdx.x * 256 + threadIdx.x;
    if (idx >= NH * HP * HP) return;
    int n = idx / (HP * HP);
    int rem = idx - n * HP * HP;
    int r = rem / HP;          // h (reduction) index
    int c = rem - r * HP;      // d (output) index
    float v = 0.f;
    if (r < HID && c < HID) v = Wma[((size_t)n * HID + r) * HID + c];
    o[idx] = v;
}

__global__ void prep_whT_k(const float* __restrict__ Wh, float* __restrict__ o) {
    int idx = blockIdx.x * 256 + threadIdx.x;
    if (idx >= NH * HP * HP) return;
    int row = idx / HP;        // n*HP + d
    int col = idx - row * HP;  // h (output) index
    int n = row / HP;
    int d = row - n * HP;
    float v = 0.f;
    if (d < HID && col < HID) v = Wh[(size_t)col * (NH * HID) + n * HID + d];
    o[idx] = v;
}

// ---------------------------------------------------------------------------
// Elementwise relu copy (float4)
// ---------------------------------------------------------------------------
__global__ void relu4_k(const float4* __restrict__ in, float4* __restrict__ out, int n4) {
    int idx = blockIdx.x * 256 + threadIdx.x;
    if (idx >= n4) return;
    float4 v = in[idx];
    v.x = fmaxf(v.x, 0.f); v.y = fmaxf(v.y, 0.f);
    v.z = fmaxf(v.z, 0.f); v.w = fmaxf(v.w, 0.f);
    out[idx] = v;
}

// ---------------------------------------------------------------------------
// Generic tiled GEMM:  C[M][ldc] = op(A[M][lda] @ B[N][ldb]^T)
// (both A and B are K-major row-major; this is the X @ W.T pattern)
// cols [N, Nzero) of C are zero-filled (for padded buffers).
// ---------------------------------------------------------------------------
template <bool ADDC, bool RELU, bool BIAS>
__global__ __launch_bounds__(256) void gemm_nt_k(
    const float* __restrict__ A, int lda,
    const float* __restrict__ B, int ldb,
    float* __restrict__ C, int ldc,
    int M, int N, int K, int Nzero,
    const float* __restrict__ bias)
{
    __shared__ __align__(16) float As[16][68];
    __shared__ __align__(16) float Bs[16][68];
    const int tid = threadIdx.x;
    const int tx = tid & 15, ty = tid >> 4;
    const int m0 = blockIdx.x * 64, n0 = blockIdx.y * 64;
    float acc[4][4] = {};

    for (int k0 = 0; k0 < K; k0 += 16) {
        {
            int r = tid >> 2;          // 0..63
            int c = (tid & 3) * 4;     // 0,4,8,12
            int gm = m0 + r;
            int gn = n0 + r;
#pragma unroll
            for (int j = 0; j < 4; ++j) {
                int gk = k0 + c + j;
                As[c + j][r] = (gm < M && gk < K) ? A[(size_t)gm * lda + gk] : 0.f;
                Bs[c + j][r] = (gn < N && gk < K) ? B[(size_t)gn * ldb + gk] : 0.f;
            }
        }
        __syncthreads();
#pragma unroll
        for (int k = 0; k < 16; ++k) {
            float a4[4], b4[4];
            *(float4*)a4 = *(const float4*)&As[k][ty * 4];
            *(float4*)b4 = *(const float4*)&Bs[k][tx * 4];
#pragma unroll
            for (int i = 0; i < 4; ++i)
#pragma unroll
                for (int j = 0; j < 4; ++j)
                    acc[i][j] += a4[i] * b4[j];
        }
        __syncthreads();
    }

#pragma unroll
    for (int i = 0; i < 4; ++i) {
        int gm = m0 + ty * 4 + i;
        if (gm >= M) continue;
#pragma unroll
        for (int j = 0; j < 4; ++j) {
            int gn = n0 + tx * 4 + j;
            if (gn < N) {
                float v = acc[i][j];
                if (BIAS) v += bias[gn];
                if (ADDC) v += C[(size_t)gm * ldc + gn];
                if (RELU) v = fmaxf(v, 0.f);
                C[(size_t)gm * ldc + gn] = v;
            } else if (gn < Nzero) {
                C[(size_t)gm * ldc + gn] = 0.f;
            }
        }
    }
}

// ---------------------------------------------------------------------------
// Fused message-passing iteration.
// Block: 16 bonds, 256 threads = 4 waves; wave owns 4 bond rows; lane owns 5 cols.
// Per head: mt = msg_tile @ Wma[n] (LDS-staged), scores via coalesced gather +
// 64-lane shfl reduce, softmax per-lane (redundant), comp via gather,
// acc += comp @ WhT[n] (LDS-staged). Epilogue: relu(binput + acc).
// ---------------------------------------------------------------------------
__global__ __launch_bounds__(256, 2) void mp_iter_k(
    const float* __restrict__ msg_in,   // [E][HP]
    const float* __restrict__ binput,   // [E][HP]
    const int*   __restrict__ bgraph,   // [E][KNB]
    const float* __restrict__ WmaP,     // [NH][HP][HP]
    const float* __restrict__ WhTP,     // [NH*HP][HP]
    float* __restrict__ msg_out)        // [E][HP]
{
    __shared__ __align__(16) float sMsg[TB][HP];
    __shared__ __align__(16) float sStage[16][HP];
    __shared__ __align__(16) float sMtc[TB][HP];
    __shared__ int sNbi[TB][KNB];

    const int tid = threadIdx.x;
    const int wv  = tid >> 6;   // wave id 0..3
    const int ln  = tid & 63;   // lane 0..63
    const int e0  = blockIdx.x * TB;
    const int r0  = wv * 4;     // this wave's first bond row in tile
    const int c0  = ln * 5;     // this lane's first column

    {
        const float4* gsrc = (const float4*)(msg_in + (size_t)e0 * HP);
        float4* sdst = (float4*)&sMsg[0][0];
#pragma unroll
        for (int i = 0; i < (TB * HP / 4) / 256; ++i)   // 5
            sdst[tid + i * 256] = gsrc[tid + i * 256];
    }
    if (tid < TB * KNB)
        sNbi[tid / KNB][tid % KNB] = bgraph[(size_t)(e0 + tid / KNB) * KNB + (tid % KNB)];
    __syncthreads();

    float acc[4][5] = {};

    for (int n = 0; n < NH; ++n) {
        // ---- mt = msg_tile @ Wma[n] ----
        const float* wma = WmaP + (size_t)n * HP * HP;
        float mt[4][5] = {};
        for (int h0 = 0; h0 < HP; h0 += 16) {
            __syncthreads();
            {
                const float4* ws_ = (const float4*)(wma + (size_t)h0 * HP);
                float4* wd = (float4*)&sStage[0][0];
#pragma unroll
                for (int i = 0; i < 5; ++i) wd[tid + i * 256] = ws_[tid + i * 256];
            }
            __syncthreads();
#pragma unroll
            for (int hh = 0; hh < 16; ++hh) {
                float a0 = sMsg[r0 + 0][h0 + hh];
                float a1 = sMsg[r0 + 1][h0 + hh];
                float a2 = sMsg[r0 + 2][h0 + hh];
                float a3 = sMsg[r0 + 3][h0 + hh];
#pragma unroll
                for (int j = 0; j < 5; ++j) {
                    float w = sStage[hh][c0 + j];
                    mt[0][j] += a0 * w;
                    mt[1][j] += a1 * w;
                    mt[2][j] += a2 * w;
                    mt[3][j] += a3 * w;
                }
            }
        }
        // write mt to sMtc (rows are wave-private; in-wave LDS ordering is
        // enforced by the compiler via lgkmcnt on the visible dependency)
#pragma unroll
        for (int r = 0; r < 4; ++r)
#pragma unroll
            for (int j = 0; j < 5; ++j)
                sMtc[r0 + r][c0 + j] = mt[r][j];

        // ---- scores: pk[r][k] = <nei_rk , mt_r> ----
        float pk[4][KNB];
#pragma unroll
        for (int r = 0; r < 4; ++r)
#pragma unroll
            for (int k = 0; k < KNB; ++k) pk[r][k] = 0.f;
#pragma unroll
        for (int k = 0; k < KNB; ++k) {
#pragma unroll
            for (int r = 0; r < 4; ++r) {
                const float* nrow = msg_in + (size_t)sNbi[r0 + r][k] * HP;
                float s = 0.f;
#pragma unroll
                for (int j = 0; j < 5; ++j)
                    s += nrow[c0 + j] * sMtc[r0 + r][c0 + j];
                pk[r][k] = s;
            }
        }
#pragma unroll
        for (int m = 1; m < 64; m <<= 1) {
#pragma unroll
            for (int r = 0; r < 4; ++r)
#pragma unroll
                for (int k = 0; k < KNB; ++k)
                    pk[r][k] += __shfl_xor(pk[r][k], m);
        }
        // ---- softmax over k (all lanes redundantly; values identical) ----
        float wgt[4][KNB];
#pragma unroll
        for (int r = 0; r < 4; ++r) {
            float mx = pk[r][0];
#pragma unroll
            for (int k = 1; k < KNB; ++k) mx = fmaxf(mx, pk[r][k]);
            float ssum = 0.f;
#pragma unroll
            for (int k = 0; k < KNB; ++k) {
                float e = __expf(pk[r][k] - mx);
                wgt[r][k] = e;
                ssum += e;
            }
            float inv = 1.f / ssum;
#pragma unroll
            for (int k = 0; k < KNB; ++k) wgt[r][k] *= inv;
        }
        // ---- comp[r][j] = sum_k w * nei ----
        float cp[4][5] = {};
#pragma unroll
        for (int k = 0; k < KNB; ++k) {
#pragma unroll
            for (int r = 0; r < 4; ++r) {
                const float* nrow = msg_in + (size_t)sNbi[r0 + r][k] * HP;
                float w = wgt[r][k];
#pragma unroll
                for (int j = 0; j < 5; ++j)
                    cp[r][j] += w * nrow[c0 + j];
            }
        }
#pragma unroll
        for (int r = 0; r < 4; ++r)
#pragma unroll
            for (int j = 0; j < 5; ++j)
                sMtc[r0 + r][c0 + j] = cp[r][j];

        // ---- acc += comp @ WhT[n] ----
        const float* wh = WhTP + (size_t)n * HP * HP;
        for (int d0 = 0; d0 < HP; d0 += 16) {
            __syncthreads();
            {
                const float4* ws_ = (const float4*)(wh + (size_t)d0 * HP);
                float4* wd = (float4*)&sStage[0][0];
#pragma unroll
                for (int i = 0; i < 5; ++i) wd[tid + i * 256] = ws_[tid + i * 256];
            }
            __syncthreads();
#pragma unroll
            for (int dd = 0; dd < 16; ++dd) {
                float a0 = sMtc[r0 + 0][d0 + dd];
                float a1 = sMtc[r0 + 1][d0 + dd];
                float a2 = sMtc[r0 + 2][d0 + dd];
                float a3 = sMtc[r0 + 3][d0 + dd];
#pragma unroll
                for (int j = 0; j < 5; ++j) {
                    float w = sStage[dd][c0 + j];
                    acc[0][j] += a0 * w;
                    acc[1][j] += a1 * w;
                    acc[2][j] += a2 * w;
                    acc[3][j] += a3 * w;
                }
            }
        }
    }

    // epilogue: relu(binput + acc)  (pad cols are 0+0 -> stay 0)
#pragma unroll
    for (int r = 0; r < 4; ++r) {
        size_t row = (size_t)(e0 + r0 + r) * HP;
#pragma unroll
        for (int j = 0; j < 5; ++j) {
            float v = binput[row + c0 + j] + acc[r][j];
            msg_out[row + c0 + j] = fmaxf(v, 0.f);
        }
    }
}

// ---------------------------------------------------------------------------
// a_nei[a][c] = sum_k message[agraph[a][k]][c]
// ---------------------------------------------------------------------------
__global__ void gather_sum_k(const float* __restrict__ msg,
                             const int* __restrict__ agraph,
                             float* __restrict__ out) {
    int idx = blockIdx.x * 256 + threadIdx.x;
    if (idx >= NATOMS * HP) return;
    int a = idx / HP, c = idx - (idx / HP) * HP;
    const int* g = agraph + (size_t)a * KNB;
    float s = 0.f;
#pragma unroll
    for (int k = 0; k < KNB; ++k)
        s += msg[(size_t)g[k] * HP + c];
    out[idx] = s;
}

// ---------------------------------------------------------------------------
// Per-molecule attention middle: scores = ah2 . cur^T, softmax rows, comp2 = w @ cur
// One block per molecule; cur staged in LDS; a-rows processed in 2 halves of 25.
// ---------------------------------------------------------------------------
__global__ __launch_bounds__(256) void mol_attn_k(
    const float* __restrict__ atomH,  // [A][HP] (cur)
    const float* __restrict__ ah2,    // [A][HP] (cur @ Wa^T)
    float* __restrict__ comp2)        // [A][HP], cols < HID written
{
    __shared__ float sCur[APM][HID + 1];  // +1 pad: stride 301 (coprime 32 banks)
    __shared__ float sS[25][52];
    const int tid = threadIdx.x;
    const int m = blockIdx.x;
    const float* cbase = atomH + (size_t)m * APM * HP;

    for (int i = tid; i < APM * HID; i += 256) {
        int a = i / HID, h = i - a * HID;
        sCur[a][h] = cbase[(size_t)a * HP + h];
    }
    __syncthreads();

    for (int ab = 0; ab < 2; ++ab) {
        for (int p = tid; p < 25 * APM; p += 256) {
            int al = p / APM, b = p - al * APM;
            const float* arow = ah2 + (size_t)(m * APM + ab * 25 + al) * HP;
            float s = 0.f;
            for (int h = 0; h < HID; ++h) s += arow[h] * sCur[b][h];
            sS[al][b] = s;
        }
        __syncthreads();
        if (tid < 25) {
            float mx = -1e30f;
            for (int b = 0; b < APM; ++b) mx = fmaxf(mx, sS[tid][b]);
            float sum = 0.f;
            for (int b = 0; b < APM; ++b) {
                float e = __expf(sS[tid][b] - mx);
                sS[tid][b] = e;
                sum += e;
            }
            float inv = 1.f / sum;
            for (int b = 0; b < APM; ++b) sS[tid][b] *= inv;
        }
        __syncthreads();
        for (int p = tid; p < 25 * HID; p += 256) {
            int al = p / HID, h = p - al * HID;
            float s = 0.f;
            for (int b = 0; b < APM; ++b) s += sS[al][b] * sCur[b][h];
            comp2[(size_t)(m * APM + ab * 25 + al) * HP + h] = s;
        }
        __syncthreads();
    }
}

// ---------------------------------------------------------------------------
// mol_vecs[m][h] = sum_a (cur + atth)[m*APM+a][h] / APM
// ---------------------------------------------------------------------------
__global__ void mol_reduce_k(const float* __restrict__ atomH,
                             const float* __restrict__ atth,
                             float* __restrict__ out) {
    const int m = blockIdx.x;
    for (int h = threadIdx.x; h < HID; h += 256) {
        float s = 0.f;
        for (int a = 0; a < APM; ++a) {
            size_t i = (size_t)(m * APM + a) * HP + h;
            s += atomH[i] + atth[i];
        }
        out[(size_t)m * HID + h] = s * (1.f / APM);
    }
}

// ---------------------------------------------------------------------------
extern "C" void kernel_launch(void* const* d_in, const int* in_sizes, int n_in,
                              void* d_out, int out_size, void* d_ws, size_t ws_size,
                              hipStream_t stream) {
    const float* fatoms = (const float*)d_in[0];
    const float* fbonds = (const float*)d_in[1];
    const int*   agraph = (const int*)d_in[2];
    const int*   bgraph = (const int*)d_in[3];
    const float* W_i    = (const float*)d_in[4];
    const float* W_ma   = (const float*)d_in[5];
    const float* W_h    = (const float*)d_in[6];
    const float* W_o    = (const float*)d_in[7];
    const float* b_o    = (const float*)d_in[8];
    const float* W_a    = (const float*)d_in[9];
    const float* W_b    = (const float*)d_in[10];
    const float* b_b    = (const float*)d_in[11];
    float* out = (float*)d_out;

    // Workspace layout (~234 MB total, heavy aliasing):
    char* ws = (char*)d_ws;
    const size_t SZ_E = (size_t)E_BONDS * HP * 4;   // 76,800,000
    const size_t SZ_A = (size_t)NATOMS * HP * 4;    // 38,400,000
    const size_t SZ_W = (size_t)NH * HP * HP * 4;   // 1,638,400
    float* binput = (float*)(ws);
    float* msgA   = (float*)(ws + SZ_E);
    float* msgB   = (float*)(ws + 2 * SZ_E);
    float* WmaP   = (float*)(ws + 3 * SZ_E);
    float* WhTP   = (float*)(ws + 3 * SZ_E + SZ_W);
    // aliases (all producers dead before reuse):
    float* aNei   = binput;                      // after last mp_iter
    float* ah2    = (float*)(ws + SZ_A);         // binput[38.4MB..76.8MB)
    float* atomH  = msgA;                        // after last mp_iter input consumed
    float* comp2  = msgB;                        // after gather_sum consumed final msg
    float* atth   = (float*)(ws + 2 * SZ_E + SZ_A);

    // 1. weight prep
    prep_wma_k<<<dim3((NH * HP * HP + 255) / 256), dim3(256), 0, stream>>>(W_ma, WmaP);
    prep_whT_k<<<dim3((NH * HP * HP + 255) / 256), dim3(256), 0, stream>>>(W_h, WhTP);

    // 2. binput = fbonds @ W_i^T (padded to HP cols); message0 = relu(binput)
    gemm_nt_k<false, false, false><<<dim3(938, 5), dim3(256), 0, stream>>>(
        fbonds, BONDIN, W_i, BONDIN, binput, HP, E_BONDS, HID, BONDIN, HP, nullptr);
    relu4_k<<<dim3(E_BONDS * HP / 4 / 256), dim3(256), 0, stream>>>(
        (const float4*)binput, (float4*)msgA, E_BONDS * HP / 4);

    // 3. three fused message-passing iterations (A->B->A->B)
    mp_iter_k<<<dim3(E_BONDS / TB), dim3(256), 0, stream>>>(msgA, binput, bgraph, WmaP, WhTP, msgB);
    mp_iter_k<<<dim3(E_BONDS / TB), dim3(256), 0, stream>>>(msgB, binput, bgraph, WmaP, WhTP, msgA);
    mp_iter_k<<<dim3(E_BONDS / TB), dim3(256), 0, stream>>>(msgA, binput, bgraph, WmaP, WhTP, msgB);

    // 4. atom stage: a_nei gather-sum; atom_hiddens = relu([fatoms,a_nei] @ W_o^T + b_o)
    gather_sum_k<<<dim3((NATOMS * HP + 255) / 256), dim3(256), 0, stream>>>(msgB, agraph, aNei);
    gemm_nt_k<false, false, false><<<dim3(469, 5), dim3(256), 0, stream>>>(
        fatoms, AFD, W_o, AFD + HID, atomH, HP, NATOMS, HID, AFD, HID, nullptr);
    gemm_nt_k<true, true, true><<<dim3(469, 5), dim3(256), 0, stream>>>(
        aNei, HP, W_o + AFD, AFD + HID, atomH, HP, NATOMS, HID, HID, HID, b_o);

    // 5. molecule attention
    gemm_nt_k<false, false, false><<<dim3(469, 5), dim3(256), 0, stream>>>(
        atomH, HP, W_a, HID, ah2, HP, NATOMS, HID, HID, HID, nullptr);
    mol_attn_k<<<dim3(NMOLS), dim3(256), 0, stream>>>(atomH, ah2, comp2);
    gemm_nt_k<false, true, true><<<dim3(469, 5), dim3(256), 0, stream>>>(
        comp2, HP, W_b, HID, atth, HP, NATOMS, HID, HID, HID, b_b);
    mol_reduce_k<<<dim3(NMOLS), dim3(256), 0, stream>>>(atomH, atth, out);
}

// Round 3
// 1405.005 us; speedup vs baseline: 7.5540x; 7.5540x over previous
//
#include <hip/hip_runtime.h>
#include <hip/hip_bf16.h>
#include <math.h>

// Problem constants
#define HID       300
#define HP        320
#define NH        4
#define E_BONDS   60000
#define NATOMS    30000
#define KNB       6
#define NMOLS     600
#define APM       50
#define AFD       144
#define BONDIN    158

typedef unsigned short u16;
typedef unsigned int   u32;
typedef _Float16 f16;
typedef f16   f16x8 __attribute__((ext_vector_type(8)));
typedef float f32x4 __attribute__((ext_vector_type(4)));

// ---------------- helpers ----------------
__device__ inline float hlo(u32 u) { union { u32 i; f16 h[2]; } c; c.i = u; return (float)c.h[0]; }
__device__ inline float hhi(u32 u) { union { u32 i; f16 h[2]; } c; c.i = u; return (float)c.h[1]; }
__device__ inline u32 packh2(float a, float b) {
    union { u32 i; f16 h[2]; } c; c.h[0] = (f16)a; c.h[1] = (f16)b; return c.i;
}

__device__ inline void gl2lds16(const void* g, void* l) {
    __builtin_amdgcn_global_load_lds(
        (const __attribute__((address_space(1))) void*)g,
        (__attribute__((address_space(3))) void*)l, 16, 0, 0);
}

// ---------------------------------------------------------------------------
// MFMA GEMM: C = A[M][lda]_f16 @ B[N][ldb]_f16^T   (B pre-transposed: [N][K])
// Tile 128x64, BK=64, 256 thr = 4 waves (2x2), wave = 64x32.
// Staging: global_load_lds width-16, linear LDS dest, source pre-swizzled;
// ds_read_b128 with matching XOR swizzle (chunk ^= row&7) -> 2-way conflicts.
// EPI: 0 Cf=v | 1 Ch=h(v) | 2 Ch=h(v),out2=h(relu v) | 3 v+=resid,relu,Ch
//      4 v+=Cf+bias,relu,Cf&Ch | 5 v+=bias,relu,Cf
// ---------------------------------------------------------------------------
template <int EPI>
__global__ __launch_bounds__(256) void mfma_gemm_k(
    const f16* __restrict__ A, int lda,
    const f16* __restrict__ B, int ldb,
    int M, int K, int ldc,
    float* __restrict__ Cf, f16* __restrict__ Ch,
    const float* __restrict__ bias,
    const f16* __restrict__ resid,
    f16* __restrict__ out2)
{
    __shared__ f16 sA[128 * 64];
    __shared__ f16 sB[64 * 64];
    const int tid  = threadIdx.x;
    const int lane = tid & 63;
    const int wv   = tid >> 6;
    const int wm   = wv >> 1, wn = wv & 1;
    const int m0   = blockIdx.x * 128, n0 = blockIdx.y * 64;

    f32x4 acc[4][2];
#pragma unroll
    for (int i = 0; i < 4; ++i)
#pragma unroll
        for (int j = 0; j < 2; ++j) acc[i][j] = (f32x4){0.f, 0.f, 0.f, 0.f};

    for (int k0 = 0; k0 < K; k0 += 64) {
        __syncthreads();
        // stage A: 16KB, 4 chunks of 1KB per wave
#pragma unroll
        for (int i = 0; i < 4; ++i) {
            int o   = (((i * 4 + wv) * 64) + lane) * 16;   // linear LDS byte off
            int row = o >> 7;
            int p   = (o >> 4) & 7;
            int gr  = m0 + row; gr = gr < M ? gr : M - 1;
            const f16* g = A + (size_t)gr * lda + k0 + ((p ^ (row & 7)) << 3);
            gl2lds16(g, (char*)sA + (i * 4 + wv) * 1024);
        }
        // stage B: 8KB
#pragma unroll
        for (int i = 0; i < 2; ++i) {
            int o   = (((i * 4 + wv) * 64) + lane) * 16;
            int row = o >> 7;
            int p   = (o >> 4) & 7;
            const f16* g = B + (size_t)(n0 + row) * ldb + k0 + ((p ^ (row & 7)) << 3);
            gl2lds16(g, (char*)sB + (i * 4 + wv) * 1024);
        }
        __syncthreads();

        const int rl = lane & 15, cl = lane >> 4;
#pragma unroll
        for (int kh = 0; kh < 2; ++kh) {
            f16x8 af[4], bfr[2];
#pragma unroll
            for (int mf = 0; mf < 4; ++mf) {
                int row = wm * 64 + mf * 16 + rl;
                int ch  = (kh * 4 + cl) ^ (row & 7);
                af[mf]  = *(const f16x8*)&sA[row * 64 + ch * 8];
            }
#pragma unroll
            for (int nf = 0; nf < 2; ++nf) {
                int row = wn * 32 + nf * 16 + rl;
                int ch  = (kh * 4 + cl) ^ (row & 7);
                bfr[nf] = *(const f16x8*)&sB[row * 64 + ch * 8];
            }
#pragma unroll
            for (int mf = 0; mf < 4; ++mf)
#pragma unroll
                for (int nf = 0; nf < 2; ++nf)
                    acc[mf][nf] = __builtin_amdgcn_mfma_f32_16x16x32_f16(
                        af[mf], bfr[nf], acc[mf][nf], 0, 0, 0);
        }
    }

    const int rl = lane & 15, cl = lane >> 4;
#pragma unroll
    for (int mf = 0; mf < 4; ++mf) {
#pragma unroll
        for (int r = 0; r < 4; ++r) {
            int gm = m0 + wm * 64 + mf * 16 + cl * 4 + r;
            if (gm >= M) continue;
#pragma unroll
            for (int nf = 0; nf < 2; ++nf) {
                int gn = n0 + wn * 32 + nf * 16 + rl;
                float v = acc[mf][nf][r];
                size_t ci = (size_t)gm * ldc + gn;
                if (EPI == 0) {
                    Cf[ci] = v;
                } else if (EPI == 1) {
                    Ch[ci] = (f16)v;
                } else if (EPI == 2) {
                    Ch[ci] = (f16)v;
                    out2[ci] = (f16)fmaxf(v, 0.f);
                } else if (EPI == 3) {
                    v += (float)resid[ci];
                    Ch[ci] = (f16)fmaxf(v, 0.f);
                } else if (EPI == 4) {
                    v += Cf[ci];
                    v += (gn < HID) ? bias[gn] : 0.f;
                    v = fmaxf(v, 0.f);
                    Cf[ci] = v; Ch[ci] = (f16)v;
                } else {
                    v += (gn < HID) ? bias[gn] : 0.f;
                    Cf[ci] = fmaxf(v, 0.f);
                }
            }
        }
    }
}

// ---------------------------------------------------------------------------
// Fused score/softmax/comp, all 4 heads, nei rows loaded once into registers.
// 256 thr = 16 bonds x 16 threads; thread owns 20 cols. comp overwrites mt
// in place (each thread reads only its own cols before writing them).
// ---------------------------------------------------------------------------
__global__ __launch_bounds__(256) void score_comp_k(
    const f16* __restrict__ msg,     // [E][320] f16
    f16* __restrict__ mtc,           // [E][1280] f16: in mt, out comp
    const int* __restrict__ bgraph)
{
    const int tid = threadIdx.x;
    const int e   = blockIdx.x * 16 + (tid >> 4);
    const int t   = tid & 15;

    u32 nei[KNB][10];
#pragma unroll
    for (int k = 0; k < KNB; ++k) {
        int nb = bgraph[e * KNB + k];
        const u32* p = (const u32*)(msg + (size_t)nb * HP) + t * 10;
#pragma unroll
        for (int j = 0; j < 10; ++j) nei[k][j] = p[j];
    }

    for (int n = 0; n < NH; ++n) {
        u32* mrow = (u32*)(mtc + (size_t)e * (NH * HP) + n * HP) + t * 10;
        u32 mt[10];
#pragma unroll
        for (int j = 0; j < 10; ++j) mt[j] = mrow[j];

        float pk[KNB] = {0.f, 0.f, 0.f, 0.f, 0.f, 0.f};
#pragma unroll
        for (int j = 0; j < 10; ++j) {
            float m0 = hlo(mt[j]), m1 = hhi(mt[j]);
#pragma unroll
            for (int k = 0; k < KNB; ++k)
                pk[k] += hlo(nei[k][j]) * m0 + hhi(nei[k][j]) * m1;
        }
#pragma unroll
        for (int s = 1; s < 16; s <<= 1)
#pragma unroll
            for (int k = 0; k < KNB; ++k) pk[k] += __shfl_xor(pk[k], s);

        float mx = pk[0];
#pragma unroll
        for (int k = 1; k < KNB; ++k) mx = fmaxf(mx, pk[k]);
        float w[KNB], sum = 0.f;
#pragma unroll
        for (int k = 0; k < KNB; ++k) { w[k] = __expf(pk[k] - mx); sum += w[k]; }
        float inv = 1.f / sum;
#pragma unroll
        for (int k = 0; k < KNB; ++k) w[k] *= inv;

#pragma unroll
        for (int j = 0; j < 10; ++j) {
            float c0 = 0.f, c1 = 0.f;
#pragma unroll
            for (int k = 0; k < KNB; ++k) {
                c0 += w[k] * hlo(nei[k][j]);
                c1 += w[k] * hhi(nei[k][j]);
            }
            mrow[j] = packh2(c0, c1);
        }
    }
}

// ---------------------------------------------------------------------------
// a_nei[a] = sum_k msg[agraph[a][k]]  (f16 in, f16 out, fp32 accum)
// ---------------------------------------------------------------------------
__global__ void gather_sum_h_k(const f16* __restrict__ msg,
                               const int* __restrict__ agraph,
                               f16* __restrict__ out) {
    int idx = blockIdx.x * 256 + threadIdx.x;   // over NATOMS*160 uint pairs
    if (idx >= NATOMS * (HP / 2)) return;
    int a = idx / (HP / 2), c = idx - a * (HP / 2);
    const int* g = agraph + (size_t)a * KNB;
    float s0 = 0.f, s1 = 0.f;
#pragma unroll
    for (int k = 0; k < KNB; ++k) {
        u32 u = *(const u32*)(msg + (size_t)g[k] * HP + c * 2);
        s0 += hlo(u); s1 += hhi(u);
    }
    ((u32*)out)[idx] = packh2(s0, s1);
}

// ---------------------------------------------------------------------------
// fp32 [R][C] -> f16 [R][CP] zero-padded
// ---------------------------------------------------------------------------
__global__ void conv_pad_k(const float* __restrict__ src, f16* __restrict__ dst,
                           int R, int C, int CP) {
    int idx = blockIdx.x * 256 + threadIdx.x;
    if (idx >= R * CP) return;
    int r = idx / CP, c = idx - r * CP;
    dst[idx] = (f16)(c < C ? src[(size_t)r * C + c] : 0.f);
}

// ---------------------------------------------------------------------------
// Weight prep -> f16, padded, K-contiguous ([N][K]) layouts.
// mode 0: WiT[320][192]  <- W_i[300][158]
// mode 1: WmaT[1280][320]<- W_ma[n][h][d] at row n*320+d, col h
// mode 2: WhT[320][1280] <- W_h[h_out][n*300+d] at row h_out, col n*320+d
// mode 3: WoA[320][192]  <- W_o[300][444] cols 0..143
// mode 4: WoB[320][320]  <- W_o cols 144..443
// else:   [320][320]     <- [300][300]
// ---------------------------------------------------------------------------
__global__ void prep_w_k(const float* __restrict__ src, f16* __restrict__ dst,
                         int mode, int R, int CK) {
    int idx = blockIdx.x * 256 + threadIdx.x;
    if (idx >= R * CK) return;
    int r = idx / CK, c = idx - r * CK;
    float v = 0.f;
    if (mode == 0) {
        if (r < HID && c < BONDIN) v = src[r * BONDIN + c];
    } else if (mode == 1) {
        int n = r / HP, d = r - n * HP;
        if (d < HID && c < HID) v = src[((size_t)n * HID + c) * HID + d];
    } else if (mode == 2) {
        int n = c / HP, d = c - n * HP;
        if (r < HID && d < HID) v = src[(size_t)r * (NH * HID) + n * HID + d];
    } else if (mode == 3) {
        if (r < HID && c < AFD) v = src[r * (AFD + HID) + c];
    } else if (mode == 4) {
        if (r < HID && c < HID) v = src[r * (AFD + HID) + AFD + c];
    } else {
        if (r < HID && c < HID) v = src[r * HID + c];
    }
    dst[idx] = (f16)v;
}

// ---------------------------------------------------------------------------
// Per-molecule attention (fp32 in, f16 comp2 out)
// ---------------------------------------------------------------------------
__global__ __launch_bounds__(256) void mol_attn_k(
    const float* __restrict__ atomH,  // [A][320]
    const float* __restrict__ ah2,    // [A][320]
    f16* __restrict__ comp2h)         // [A][320] f16 (cols < HID written)
{
    __shared__ float sCur[APM][HID + 1];
    __shared__ float sS[25][52];
    const int tid = threadIdx.x;
    const int m = blockIdx.x;
    const float* cbase = atomH + (size_t)m * APM * HP;

    for (int i = tid; i < APM * HID; i += 256) {
        int a = i / HID, h = i - a * HID;
        sCur[a][h] = cbase[(size_t)a * HP + h];
    }
    __syncthreads();

    for (int ab = 0; ab < 2; ++ab) {
        for (int p = tid; p < 25 * APM; p += 256) {
            int al = p / APM, b = p - al * APM;
            const float* arow = ah2 + (size_t)(m * APM + ab * 25 + al) * HP;
            float s = 0.f;
            for (int h = 0; h < HID; ++h) s += arow[h] * sCur[b][h];
            sS[al][b] = s;
        }
        __syncthreads();
        if (tid < 25) {
            float mx = -1e30f;
            for (int b = 0; b < APM; ++b) mx = fmaxf(mx, sS[tid][b]);
            float sum = 0.f;
            for (int b = 0; b < APM; ++b) {
                float e = __expf(sS[tid][b] - mx);
                sS[tid][b] = e; sum += e;
            }
            float inv = 1.f / sum;
            for (int b = 0; b < APM; ++b) sS[tid][b] *= inv;
        }
        __syncthreads();
        for (int p = tid; p < 25 * HID; p += 256) {
            int al = p / HID, h = p - al * HID;
            float s = 0.f;
            for (int b = 0; b < APM; ++b) s += sS[al][b] * sCur[b][h];
            comp2h[(size_t)(m * APM + ab * 25 + al) * HP + h] = (f16)s;
        }
        __syncthreads();
    }
}

__global__ void mol_reduce_k(const float* __restrict__ atomH,
                             const float* __restrict__ atth,
                             float* __restrict__ out) {
    const int m = blockIdx.x;
    for (int h = threadIdx.x; h < HID; h += 256) {
        float s = 0.f;
        for (int a = 0; a < APM; ++a) {
            size_t i = (size_t)(m * APM + a) * HP + h;
            s += atomH[i] + atth[i];
        }
        out[(size_t)m * HID + h] = s * (1.f / APM);
    }
}

// ---------------------------------------------------------------------------
extern "C" void kernel_launch(void* const* d_in, const int* in_sizes, int n_in,
                              void* d_out, int out_size, void* d_ws, size_t ws_size,
                              hipStream_t stream) {
    const float* fatoms = (const float*)d_in[0];
    const float* fbonds = (const float*)d_in[1];
    const int*   agraph = (const int*)d_in[2];
    const int*   bgraph = (const int*)d_in[3];
    const float* W_i    = (const float*)d_in[4];
    const float* W_ma   = (const float*)d_in[5];
    const float* W_h    = (const float*)d_in[6];
    const float* W_o    = (const float*)d_in[7];
    const float* b_o    = (const float*)d_in[8];
    const float* W_a    = (const float*)d_in[9];
    const float* W_b    = (const float*)d_in[10];
    const float* b_b    = (const float*)d_in[11];
    float* out = (float*)d_out;

    // ---- workspace layout (max 232,898,560 B) ----
    char* ws = (char*)d_ws;
    // region A [0, 153.6MB): fbonds_h -> mt_all/comp_all -> tail buffers
    f16* fbondsh = (f16*)ws;
    f16* mtall   = (f16*)ws;
    f16* aneih   = (f16*)ws;                         // [30000][320] f16
    f16* fatomsh = (f16*)(ws + 19200000);            // [30000][192] f16
    float* atomH = (float*)(ws + 30720000);          // [30000][320] f32
    f16* atomHh  = (f16*)(ws + 69120000);            // [30000][320] f16
    float* ah2   = (float*)(ws + 88320000);          // [30000][320] f32
    f16* comp2h  = (f16*)(ws + 126720000);           // [30000][320] f16
    // region B [153.6MB, 192MB): binput f16; later atth f32
    f16* binh    = (f16*)(ws + 153600000);
    float* atth  = (float*)(ws + 153600000);
    // region C [192MB, 230.4MB): msg f16
    f16* msgh    = (f16*)(ws + 192000000);
    // region W [230.4MB, ~232.9MB): weights f16
    char* wb = ws + 230400000;
    f16* WiT  = (f16*)(wb);
    f16* WmaT = (f16*)(wb + 122880);
    f16* WhT  = (f16*)(wb + 942080);
    f16* WoA  = (f16*)(wb + 1761280);
    f16* WoB  = (f16*)(wb + 1884160);
    f16* Wa   = (f16*)(wb + 2088960);
    f16* Wb   = (f16*)(wb + 2293760);

    // ---- weight/input prep ----
    prep_w_k<<<dim3((320 * 192 + 255) / 256), dim3(256), 0, stream>>>(W_i, WiT, 0, 320, 192);
    prep_w_k<<<dim3((1280 * 320 + 255) / 256), dim3(256), 0, stream>>>(W_ma, WmaT, 1, 1280, 320);
    prep_w_k<<<dim3((320 * 1280 + 255) / 256), dim3(256), 0, stream>>>(W_h, WhT, 2, 320, 1280);
    prep_w_k<<<dim3((320 * 192 + 255) / 256), dim3(256), 0, stream>>>(W_o, WoA, 3, 320, 192);
    prep_w_k<<<dim3((320 * 320 + 255) / 256), dim3(256), 0, stream>>>(W_o, WoB, 4, 320, 320);
    prep_w_k<<<dim3((320 * 320 + 255) / 256), dim3(256), 0, stream>>>(W_a, Wa, 5, 320, 320);
    prep_w_k<<<dim3((320 * 320 + 255) / 256), dim3(256), 0, stream>>>(W_b, Wb, 6, 320, 320);
    conv_pad_k<<<dim3((E_BONDS * 192 + 255) / 256), dim3(256), 0, stream>>>(
        fbonds, fbondsh, E_BONDS, BONDIN, 192);

    // ---- binput/message0 ----
    mfma_gemm_k<2><<<dim3(469, 5), dim3(256), 0, stream>>>(
        fbondsh, 192, WiT, 192, E_BONDS, 192, HP, nullptr, binh, nullptr, nullptr, msgh);

    // ---- 3 message-passing iterations ----
    for (int it = 0; it < 3; ++it) {
        mfma_gemm_k<1><<<dim3(469, 20), dim3(256), 0, stream>>>(
            msgh, HP, WmaT, HP, E_BONDS, HP, NH * HP, nullptr, mtall, nullptr, nullptr, nullptr);
        score_comp_k<<<dim3(E_BONDS / 16), dim3(256), 0, stream>>>(msgh, mtall, bgraph);
        mfma_gemm_k<3><<<dim3(469, 5), dim3(256), 0, stream>>>(
            mtall, NH * HP, WhT, NH * HP, E_BONDS, NH * HP, HP, nullptr, msgh, nullptr, binh, nullptr);
    }

    // ---- atom stage ----
    gather_sum_h_k<<<dim3((NATOMS * 160 + 255) / 256), dim3(256), 0, stream>>>(msgh, agraph, aneih);
    conv_pad_k<<<dim3((NATOMS * 192 + 255) / 256), dim3(256), 0, stream>>>(
        fatoms, fatomsh, NATOMS, AFD, 192);
    mfma_gemm_k<0><<<dim3(235, 5), dim3(256), 0, stream>>>(
        fatomsh, 192, WoA, 192, NATOMS, 192, HP, atomH, nullptr, nullptr, nullptr, nullptr);
    mfma_gemm_k<4><<<dim3(235, 5), dim3(256), 0, stream>>>(
        aneih, HP, WoB, HP, NATOMS, HP, HP, atomH, atomHh, b_o, nullptr, nullptr);

    // ---- molecule attention ----
    mfma_gemm_k<0><<<dim3(235, 5), dim3(256), 0, stream>>>(
        atomHh, HP, Wa, HP, NATOMS, HP, HP, ah2, nullptr, nullptr, nullptr, nullptr);
    mol_attn_k<<<dim3(NMOLS), dim3(256), 0, stream>>>(atomH, ah2, comp2h);
    mfma_gemm_k<5><<<dim3(235, 5), dim3(256), 0, stream>>>(
        comp2h, HP, Wb, HP, NATOMS, HP, HP, atth, nullptr, b_b, nullptr, nullptr);
    mol_reduce_k<<<dim3(NMOLS), dim3(256), 0, stream>>>(atomH, atth, out);
}

// Round 4
// 1121.675 us; speedup vs baseline: 9.4621x; 1.2526x over previous
//
#include <hip/hip_runtime.h>
#include <hip/hip_bf16.h>
#include <math.h>

// Problem constants
#define HID       300
#define HP        320
#define NH        4
#define E_BONDS   60000
#define NATOMS    30000
#define KNB       6
#define NMOLS     600
#define APM       50
#define AFD       144
#define BONDIN    158

typedef unsigned short u16;
typedef unsigned int   u32;
typedef _Float16 f16;
typedef f16   f16x8 __attribute__((ext_vector_type(8)));
typedef float f32x4 __attribute__((ext_vector_type(4)));

// ---------------- helpers ----------------
__device__ inline float hlo(u32 u) { union { u32 i; f16 h[2]; } c; c.i = u; return (float)c.h[0]; }
__device__ inline float hhi(u32 u) { union { u32 i; f16 h[2]; } c; c.i = u; return (float)c.h[1]; }
__device__ inline u32 packh2(float a, float b) {
    union { u32 i; f16 h[2]; } c; c.h[0] = (f16)a; c.h[1] = (f16)b; return c.i;
}

__device__ inline void gl2lds16(const void* g, void* l) {
    __builtin_amdgcn_global_load_lds(
        (const __attribute__((address_space(1))) void*)g,
        (__attribute__((address_space(3))) void*)l, 16, 0, 0);
}

// ---------------------------------------------------------------------------
// MFMA GEMM: C = A[M][lda]_f16 @ B[Nb][ldb]_f16^T   (B pre-transposed: [N][K])
// Tile 128xBN, BK=64, 256 thr = 4 waves (2x2), wave = 64 x BN/2.
// Staging: global_load_lds width-16, linear LDS dest, source pre-swizzled;
// ds_read_b128 with matching XOR swizzle (chunk ^= row&7) -> conflict-free.
// EPI: 0 Cf=v | 1 Ch=h(v) | 2 Ch=h(v),out2=h(relu v) | 3 v+=resid,relu,Ch
//      4 v+=Cf+bias,relu,Cf&Ch | 5 v+=bias,relu,Cf
// ---------------------------------------------------------------------------
template <int BN, int EPI>
__global__ __launch_bounds__(256) void mfma_gemm_k(
    const f16* __restrict__ A, int lda,
    const f16* __restrict__ B, int ldb,
    int M, int Nb, int K, int ldc,
    float* __restrict__ Cf, f16* __restrict__ Ch,
    const float* __restrict__ bias,
    const f16* __restrict__ resid,
    f16* __restrict__ out2)
{
    constexpr int NF = BN / 32;            // n-fragments per wave
    __shared__ f16 sA[128 * 64];
    __shared__ f16 sB[BN * 64];
    const int tid  = threadIdx.x;
    const int lane = tid & 63;
    const int wv   = tid >> 6;
    const int wm   = wv >> 1, wn = wv & 1;
    const int m0   = blockIdx.x * 128, n0 = blockIdx.y * BN;

    f32x4 acc[4][NF];
#pragma unroll
    for (int i = 0; i < 4; ++i)
#pragma unroll
        for (int j = 0; j < NF; ++j) acc[i][j] = (f32x4){0.f, 0.f, 0.f, 0.f};

    for (int k0 = 0; k0 < K; k0 += 64) {
        __syncthreads();
        // stage A: 16KB, 4 chunks of 1KB per wave
#pragma unroll
        for (int i = 0; i < 4; ++i) {
            int o   = (((i * 4 + wv) * 64) + lane) * 16;   // linear LDS byte off
            int row = o >> 7;
            int p   = (o >> 4) & 7;
            int gr  = m0 + row; gr = gr < M ? gr : M - 1;
            const f16* g = A + (size_t)gr * lda + k0 + ((p ^ (row & 7)) << 3);
            gl2lds16(g, (char*)sA + (i * 4 + wv) * 1024);
        }
        // stage B: BN*128 bytes
#pragma unroll
        for (int i = 0; i < BN / 32; ++i) {
            int o   = (((i * 4 + wv) * 64) + lane) * 16;
            int row = o >> 7;
            int p   = (o >> 4) & 7;
            int gr  = n0 + row; gr = gr < Nb ? gr : Nb - 1;
            const f16* g = B + (size_t)gr * ldb + k0 + ((p ^ (row & 7)) << 3);
            gl2lds16(g, (char*)sB + (i * 4 + wv) * 1024);
        }
        __syncthreads();

        const int rl = lane & 15, cl = lane >> 4;
#pragma unroll
        for (int kh = 0; kh < 2; ++kh) {
            f16x8 af[4], bfr[NF];
#pragma unroll
            for (int mf = 0; mf < 4; ++mf) {
                int row = wm * 64 + mf * 16 + rl;
                int ch  = (kh * 4 + cl) ^ (row & 7);
                af[mf]  = *(const f16x8*)&sA[row * 64 + ch * 8];
            }
#pragma unroll
            for (int nf = 0; nf < NF; ++nf) {
                int row = wn * (BN / 2) + nf * 16 + rl;
                int ch  = (kh * 4 + cl) ^ (row & 7);
                bfr[nf] = *(const f16x8*)&sB[row * 64 + ch * 8];
            }
#pragma unroll
            for (int mf = 0; mf < 4; ++mf)
#pragma unroll
                for (int nf = 0; nf < NF; ++nf)
                    acc[mf][nf] = __builtin_amdgcn_mfma_f32_16x16x32_f16(
                        af[mf], bfr[nf], acc[mf][nf], 0, 0, 0);
        }
    }

    const int rl = lane & 15, cl = lane >> 4;
#pragma unroll
    for (int mf = 0; mf < 4; ++mf) {
#pragma unroll
        for (int r = 0; r < 4; ++r) {
            int gm = m0 + wm * 64 + mf * 16 + cl * 4 + r;
            if (gm >= M) continue;
#pragma unroll
            for (int nf = 0; nf < NF; ++nf) {
                int gn = n0 + wn * (BN / 2) + nf * 16 + rl;
                if (gn >= ldc) continue;
                float v = acc[mf][nf][r];
                size_t ci = (size_t)gm * ldc + gn;
                if (EPI == 0) {
                    Cf[ci] = v;
                } else if (EPI == 1) {
                    Ch[ci] = (f16)v;
                } else if (EPI == 2) {
                    Ch[ci] = (f16)v;
                    out2[ci] = (f16)fmaxf(v, 0.f);
                } else if (EPI == 3) {
                    v += (float)resid[ci];
                    Ch[ci] = (f16)fmaxf(v, 0.f);
                } else if (EPI == 4) {
                    v += Cf[ci];
                    v += (gn < HID) ? bias[gn] : 0.f;
                    v = fmaxf(v, 0.f);
                    Cf[ci] = v; Ch[ci] = (f16)v;
                } else {
                    v += (gn < HID) ? bias[gn] : 0.f;
                    Cf[ci] = fmaxf(v, 0.f);
                }
            }
        }
    }
}

// ---------------------------------------------------------------------------
// Fused score/softmax/comp, all 4 heads, nei rows loaded once into registers.
// ---------------------------------------------------------------------------
__global__ __launch_bounds__(256) void score_comp_k(
    const f16* __restrict__ msg,     // [E][320] f16
    f16* __restrict__ mtc,           // [E][1280] f16: in mt, out comp
    const int* __restrict__ bgraph)
{
    const int tid = threadIdx.x;
    const int e   = blockIdx.x * 16 + (tid >> 4);
    const int t   = tid & 15;

    u32 nei[KNB][10];
#pragma unroll
    for (int k = 0; k < KNB; ++k) {
        int nb = bgraph[e * KNB + k];
        const u32* p = (const u32*)(msg + (size_t)nb * HP) + t * 10;
#pragma unroll
        for (int j = 0; j < 10; ++j) nei[k][j] = p[j];
    }

    for (int n = 0; n < NH; ++n) {
        u32* mrow = (u32*)(mtc + (size_t)e * (NH * HP) + n * HP) + t * 10;
        u32 mt[10];
#pragma unroll
        for (int j = 0; j < 10; ++j) mt[j] = mrow[j];

        float pk[KNB] = {0.f, 0.f, 0.f, 0.f, 0.f, 0.f};
#pragma unroll
        for (int j = 0; j < 10; ++j) {
            float m0 = hlo(mt[j]), m1 = hhi(mt[j]);
#pragma unroll
            for (int k = 0; k < KNB; ++k)
                pk[k] += hlo(nei[k][j]) * m0 + hhi(nei[k][j]) * m1;
        }
#pragma unroll
        for (int s = 1; s < 16; s <<= 1)
#pragma unroll
            for (int k = 0; k < KNB; ++k) pk[k] += __shfl_xor(pk[k], s);

        float mx = pk[0];
#pragma unroll
        for (int k = 1; k < KNB; ++k) mx = fmaxf(mx, pk[k]);
        float w[KNB], sum = 0.f;
#pragma unroll
        for (int k = 0; k < KNB; ++k) { w[k] = __expf(pk[k] - mx); sum += w[k]; }
        float inv = 1.f / sum;
#pragma unroll
        for (int k = 0; k < KNB; ++k) w[k] *= inv;

#pragma unroll
        for (int j = 0; j < 10; ++j) {
            float c0 = 0.f, c1 = 0.f;
#pragma unroll
            for (int k = 0; k < KNB; ++k) {
                c0 += w[k] * hlo(nei[k][j]);
                c1 += w[k] * hhi(nei[k][j]);
            }
            mrow[j] = packh2(c0, c1);
        }
    }
}

// ---------------------------------------------------------------------------
// a_nei[a] = sum_k msg[agraph[a][k]]
// ---------------------------------------------------------------------------
__global__ void gather_sum_h_k(const f16* __restrict__ msg,
                               const int* __restrict__ agraph,
                               f16* __restrict__ out) {
    int idx = blockIdx.x * 256 + threadIdx.x;
    if (idx >= NATOMS * (HP / 2)) return;
    int a = idx / (HP / 2), c = idx - a * (HP / 2);
    const int* g = agraph + (size_t)a * KNB;
    float s0 = 0.f, s1 = 0.f;
#pragma unroll
    for (int k = 0; k < KNB; ++k) {
        u32 u = *(const u32*)(msg + (size_t)g[k] * HP + c * 2);
        s0 += hlo(u); s1 += hhi(u);
    }
    ((u32*)out)[idx] = packh2(s0, s1);
}

// ---------------------------------------------------------------------------
__global__ void conv_pad_k(const float* __restrict__ src, f16* __restrict__ dst,
                           int R, int C, int CP) {
    int idx = blockIdx.x * 256 + threadIdx.x;
    if (idx >= R * CP) return;
    int r = idx / CP, c = idx - r * CP;
    dst[idx] = (f16)(c < C ? src[(size_t)r * C + c] : 0.f);
}

// ---------------------------------------------------------------------------
// Weight prep -> f16, padded, K-contiguous ([N][K]) layouts. (see round 3)
// ---------------------------------------------------------------------------
__global__ void prep_w_k(const float* __restrict__ src, f16* __restrict__ dst,
                         int mode, int R, int CK) {
    int idx = blockIdx.x * 256 + threadIdx.x;
    if (idx >= R * CK) return;
    int r = idx / CK, c = idx - r * CK;
    float v = 0.f;
    if (mode == 0) {
        if (r < HID && c < BONDIN) v = src[r * BONDIN + c];
    } else if (mode == 1) {
        int n = r / HP, d = r - n * HP;
        if (d < HID && c < HID) v = src[((size_t)n * HID + c) * HID + d];
    } else if (mode == 2) {
        int n = c / HP, d = c - n * HP;
        if (r < HID && d < HID) v = src[(size_t)r * (NH * HID) + n * HID + d];
    } else if (mode == 3) {
        if (r < HID && c < AFD) v = src[r * (AFD + HID) + c];
    } else if (mode == 4) {
        if (r < HID && c < HID) v = src[r * (AFD + HID) + AFD + c];
    } else {
        if (r < HID && c < HID) v = src[r * HID + c];
    }
    dst[idx] = (f16)v;
}

// ---------------------------------------------------------------------------
// MFMA molecule attention: one block per molecule.
// scores[64][64] = ah2h[m rows 0..63] @ cur^T via mfma 16x16x32 (Q from global,
// cur LDS XOR-swizzled); softmax in-fragment (mask b>=50, shfl_xor reduce over
// 16-lane col groups); P -> sP LDS; PV on VALU (thread = (a, 2x40 h-slice)).
// ---------------------------------------------------------------------------
__global__ __launch_bounds__(256) void mol_attn_mfma_k(
    const f16* __restrict__ atomHh,  // [A][320] cur
    const f16* __restrict__ ah2h,    // [A][320] cur @ Wa^T
    f16* __restrict__ comp2h)        // [A][320]
{
    __shared__ f16 sCur[64 * 320];   // rows 0..63, 40 16B-chunks/row, XOR-swz
    __shared__ float sP[64][66];
    const int tid  = threadIdx.x;
    const int lane = tid & 63;
    const int wv   = tid >> 6;
    const int m    = blockIdx.x;
    const int rl   = lane & 15, cl = lane >> 4;

    // stage cur rows m*50..m*50+63 (clamped; rows >=50 garbage, masked below)
#pragma unroll
    for (int i = 0; i < 10; ++i) {
        int g   = i * 256 + wv * 64 + lane;          // chunk id 0..2559
        int row = g / 40, c = g - row * 40;
        int grow = m * APM + row; grow = grow < NATOMS ? grow : NATOMS - 1;
        const f16* src = atomHh + (size_t)grow * HP + ((c ^ (row & 7)) << 3);
        gl2lds16(src, (char*)sCur + (size_t)(i * 256 + wv * 64) * 16);
    }
    __syncthreads();

    // ---- scores: wave wv owns rows a in [16wv, 16wv+16), cols b 0..63 ----
    f32x4 acc[4];
#pragma unroll
    for (int nf = 0; nf < 4; ++nf) acc[nf] = (f32x4){0.f, 0.f, 0.f, 0.f};
    int qrow = m * APM + wv * 16 + rl;
    qrow = qrow < NATOMS ? qrow : NATOMS - 1;
    const f16* qbase = ah2h + (size_t)qrow * HP;
#pragma unroll
    for (int kh = 0; kh < 10; ++kh) {
        f16x8 aq = *(const f16x8*)(qbase + kh * 32 + cl * 8);
#pragma unroll
        for (int nf = 0; nf < 4; ++nf) {
            int brow = nf * 16 + rl;
            int ch   = (kh * 4 + cl) ^ (brow & 7);
            f16x8 bv = *(const f16x8*)&sCur[brow * 320 + ch * 8];
            acc[nf] = __builtin_amdgcn_mfma_f32_16x16x32_f16(aq, bv, acc[nf], 0, 0, 0);
        }
    }

    // ---- softmax over b per row; write P to sP ----
#pragma unroll
    for (int r = 0; r < 4; ++r) {
        float s[4];
#pragma unroll
        for (int nf = 0; nf < 4; ++nf) {
            s[nf] = acc[nf][r];
            if (nf == 3 && rl >= 2) s[nf] = -1e30f;   // mask b >= 50
        }
        float mx = fmaxf(fmaxf(s[0], s[1]), fmaxf(s[2], s[3]));
#pragma unroll
        for (int msk = 1; msk < 16; msk <<= 1) mx = fmaxf(mx, __shfl_xor(mx, msk));
        float e[4], sum = 0.f;
#pragma unroll
        for (int nf = 0; nf < 4; ++nf) { e[nf] = __expf(s[nf] - mx); sum += e[nf]; }
#pragma unroll
        for (int msk = 1; msk < 16; msk <<= 1) sum += __shfl_xor(sum, msk);
        float inv = 1.f / sum;
        int a = wv * 16 + cl * 4 + r;
#pragma unroll
        for (int nf = 0; nf < 4; ++nf) sP[a][nf * 16 + rl] = e[nf] * inv;
    }
    __syncthreads();

    // ---- PV: thread = (a = tid>>2, hq = tid&3), 2 passes x 40 h ----
    const int a  = tid >> 2, hq = tid & 3;
    const bool aval = a < APM;
    const size_t orow = (size_t)(m * APM + a) * HP;
#pragma unroll
    for (int p = 0; p < 2; ++p) {
        float av[40];
#pragma unroll
        for (int i = 0; i < 40; ++i) av[i] = 0.f;
        const int ch0 = p * 20 + hq * 5;
        for (int b = 0; b < APM; ++b) {
            float w = sP[a][b];
#pragma unroll
            for (int i = 0; i < 5; ++i) {
                int ch = (ch0 + i) ^ (b & 7);
                f16x8 cv = *(const f16x8*)&sCur[b * 320 + ch * 8];
#pragma unroll
                for (int j = 0; j < 8; ++j) av[i * 8 + j] += w * (float)cv[j];
            }
        }
        if (aval) {
#pragma unroll
            for (int i = 0; i < 5; ++i) {
                f16x8 o;
#pragma unroll
                for (int j = 0; j < 8; ++j) o[j] = (f16)av[i * 8 + j];
                *(f16x8*)&comp2h[orow + p * 160 + hq * 40 + i * 8] = o;
            }
        }
    }
}

__global__ void mol_reduce_k(const float* __restrict__ atomH,
                             const float* __restrict__ atth,
                             float* __restrict__ out) {
    const int m = blockIdx.x;
    for (int h = threadIdx.x; h < HID; h += 256) {
        float s = 0.f;
        for (int a = 0; a < APM; ++a) {
            size_t i = (size_t)(m * APM + a) * HP + h;
            s += atomH[i] + atth[i];
        }
        out[(size_t)m * HID + h] = s * (1.f / APM);
    }
}

// ---------------------------------------------------------------------------
extern "C" void kernel_launch(void* const* d_in, const int* in_sizes, int n_in,
                              void* d_out, int out_size, void* d_ws, size_t ws_size,
                              hipStream_t stream) {
    const float* fatoms = (const float*)d_in[0];
    const float* fbonds = (const float*)d_in[1];
    const int*   agraph = (const int*)d_in[2];
    const int*   bgraph = (const int*)d_in[3];
    const float* W_i    = (const float*)d_in[4];
    const float* W_ma   = (const float*)d_in[5];
    const float* W_h    = (const float*)d_in[6];
    const float* W_o    = (const float*)d_in[7];
    const float* b_o    = (const float*)d_in[8];
    const float* W_a    = (const float*)d_in[9];
    const float* W_b    = (const float*)d_in[10];
    const float* b_b    = (const float*)d_in[11];
    float* out = (float*)d_out;

    // ---- workspace layout ----
    char* ws = (char*)d_ws;
    f16* fbondsh = (f16*)ws;
    f16* mtall   = (f16*)ws;
    f16* aneih   = (f16*)ws;                         // [30000][320] f16
    f16* fatomsh = (f16*)(ws + 19200000);            // [30000][192] f16
    float* atomH = (float*)(ws + 30720000);          // [30000][320] f32
    f16* atomHh  = (f16*)(ws + 69120000);            // [30000][320] f16
    f16* ah2h    = (f16*)(ws + 88320000);            // [30000][320] f16
    f16* comp2h  = (f16*)(ws + 126720000);           // [30000][320] f16
    f16* binh    = (f16*)(ws + 153600000);
    float* atth  = (float*)(ws + 153600000);
    f16* msgh    = (f16*)(ws + 192000000);
    char* wb = ws + 230400000;
    f16* WiT  = (f16*)(wb);
    f16* WmaT = (f16*)(wb + 122880);
    f16* WhT  = (f16*)(wb + 942080);
    f16* WoA  = (f16*)(wb + 1761280);
    f16* WoB  = (f16*)(wb + 1884160);
    f16* Wa   = (f16*)(wb + 2088960);
    f16* Wb   = (f16*)(wb + 2293760);

    // ---- weight/input prep ----
    prep_w_k<<<dim3((320 * 192 + 255) / 256), dim3(256), 0, stream>>>(W_i, WiT, 0, 320, 192);
    prep_w_k<<<dim3((1280 * 320 + 255) / 256), dim3(256), 0, stream>>>(W_ma, WmaT, 1, 1280, 320);
    prep_w_k<<<dim3((320 * 1280 + 255) / 256), dim3(256), 0, stream>>>(W_h, WhT, 2, 320, 1280);
    prep_w_k<<<dim3((320 * 192 + 255) / 256), dim3(256), 0, stream>>>(W_o, WoA, 3, 320, 192);
    prep_w_k<<<dim3((320 * 320 + 255) / 256), dim3(256), 0, stream>>>(W_o, WoB, 4, 320, 320);
    prep_w_k<<<dim3((320 * 320 + 255) / 256), dim3(256), 0, stream>>>(W_a, Wa, 5, 320, 320);
    prep_w_k<<<dim3((320 * 320 + 255) / 256), dim3(256), 0, stream>>>(W_b, Wb, 6, 320, 320);
    conv_pad_k<<<dim3((E_BONDS * 192 + 255) / 256), dim3(256), 0, stream>>>(
        fbonds, fbondsh, E_BONDS, BONDIN, 192);

    // ---- binput/message0 ----
    mfma_gemm_k<128, 2><<<dim3(469, 3), dim3(256), 0, stream>>>(
        fbondsh, 192, WiT, 192, E_BONDS, 320, 192, HP, nullptr, binh, nullptr, nullptr, msgh);

    // ---- 3 message-passing iterations ----
    for (int it = 0; it < 3; ++it) {
        mfma_gemm_k<128, 1><<<dim3(469, 10), dim3(256), 0, stream>>>(
            msgh, HP, WmaT, HP, E_BONDS, NH * HP, HP, NH * HP, nullptr, mtall, nullptr, nullptr, nullptr);
        score_comp_k<<<dim3(E_BONDS / 16), dim3(256), 0, stream>>>(msgh, mtall, bgraph);
        mfma_gemm_k<128, 3><<<dim3(469, 3), dim3(256), 0, stream>>>(
            mtall, NH * HP, WhT, NH * HP, E_BONDS, HP, NH * HP, HP, nullptr, msgh, nullptr, binh, nullptr);
    }

    // ---- atom stage ----
    gather_sum_h_k<<<dim3((NATOMS * 160 + 255) / 256), dim3(256), 0, stream>>>(msgh, agraph, aneih);
    conv_pad_k<<<dim3((NATOMS * 192 + 255) / 256), dim3(256), 0, stream>>>(
        fatoms, fatomsh, NATOMS, AFD, 192);
    mfma_gemm_k<128, 0><<<dim3(235, 3), dim3(256), 0, stream>>>(
        fatomsh, 192, WoA, 192, NATOMS, 320, 192, HP, atomH, nullptr, nullptr, nullptr, nullptr);
    mfma_gemm_k<128, 4><<<dim3(235, 3), dim3(256), 0, stream>>>(
        aneih, HP, WoB, HP, NATOMS, 320, HP, HP, atomH, atomHh, b_o, nullptr, nullptr);

    // ---- molecule attention ----
    mfma_gemm_k<128, 1><<<dim3(235, 3), dim3(256), 0, stream>>>(
        atomHh, HP, Wa, HP, NATOMS, 320, HP, HP, nullptr, ah2h, nullptr, nullptr, nullptr);
    mol_attn_mfma_k<<<dim3(NMOLS), dim3(256), 0, stream>>>(atomHh, ah2h, comp2h);
    mfma_gemm_k<128, 5><<<dim3(235, 3), dim3(256), 0, stream>>>(
        comp2h, HP, Wb, HP, NATOMS, 320, HP, HP, atth, nullptr, b_b, nullptr, nullptr);
    mol_reduce_k<<<dim3(NMOLS), dim3(256), 0, stream>>>(atomH, atth, out);
}